// Round 5
// baseline (1081.810 us; speedup 1.0000x reference)
//
#include <hip/hip_runtime.h>

#define D_DIM 512
#define H_HEADS 16
#define K_EDGES 32

// ws layout (floats):
//   wT    [0, 16384)        wT[h*512 + d], h<16 -> nonneg(q_w[h][d]), h>=16 -> nonneg(k_w[h-16][d])
//   nv    [16384, 24576)    nv[d*16 + h] = nonneg(v_w[d][h])
//   nbias [24576, 25088)
//   nes   [25088, 25104)    nonneg(ego_scale[h])
//   qemb  [25104, 25104 + N*16)
//   kemb  [25104 + N*16, 25104 + 2*N*16)

__device__ __forceinline__ float nonneg_precise(float w) {
    return w > 0.0f ? w + 1.0f : expf(w);   // == elu(w)+1 exactly
}

// ---------------- K1: weight prep ----------------
__global__ void prep_kernel(const float* __restrict__ qw, const float* __restrict__ kw,
                            const float* __restrict__ vw, const float* __restrict__ es,
                            const float* __restrict__ bias, float* __restrict__ ws) {
    int idx = blockIdx.x * blockDim.x + threadIdx.x;
    if (idx < 16384) {
        int h = idx >> 9, d = idx & 511;
        float v = (h < 16) ? qw[h * 512 + d] : kw[(h - 16) * 512 + d];
        ws[idx] = nonneg_precise(v);
    } else if (idx < 24576) {
        ws[idx] = nonneg_precise(vw[idx - 16384]);
    } else if (idx < 25088) {
        ws[idx] = nonneg_precise(bias[idx - 24576]);
    } else if (idx < 25104) {
        ws[idx] = nonneg_precise(es[idx - 25088]);
    }
}

// ---------------- K2: embeddings (restructured) ----------------
// blockIdx = (node_block, h_group): 4 h-groups of 8 heads; block = 256 threads,
// covers 512 nodes. Thread: 2 nodes x 8 heads. Weights for the h-group staged
// once in LDS (16KB); inner reads are wave-uniform ds_read_b128 broadcasts, and
// each weight b128 feeds 8 FMAs (2 nodes x 4 d). x read per-thread as 8
// consecutive float4 = one full 128B line (fully consumed, no thrash).
#define EMB_TPB 256
#define NPB 512   // nodes per block

__global__ __launch_bounds__(EMB_TPB)
void embed_kernel(const float* __restrict__ x, const float* __restrict__ ws,
                  float* __restrict__ qemb, float* __restrict__ kemb, int n_nodes) {
    __shared__ float wlds[8 * D_DIM];   // 16 KB
    const int t  = threadIdx.x;
    const int hg = blockIdx.x & 3;
    const int nb = blockIdx.x >> 2;

    // stage this h-group's 8 weight rows (contiguous in wT)
    {
        const float4* src = reinterpret_cast<const float4*>(ws + (size_t)hg * 8 * D_DIM);
        float4* dst = reinterpret_cast<float4*>(wlds);
#pragma unroll
        for (int i = 0; i < 4; ++i) dst[t + i * EMB_TPB] = src[t + i * EMB_TPB];
    }
    __syncthreads();

    const int n0 = nb * NPB + t;
    const int n1 = n0 + EMB_TPB;
    const int n0c = (n0 < n_nodes) ? n0 : 0;   // clamp loads, guard stores
    const int n1c = (n1 < n_nodes) ? n1 : 0;
    const float4* xr0 = reinterpret_cast<const float4*>(x + (size_t)n0c * D_DIM);
    const float4* xr1 = reinterpret_cast<const float4*>(x + (size_t)n1c * D_DIM);

    float acc_a[8], acc_b[8];
#pragma unroll
    for (int h = 0; h < 8; ++h) { acc_a[h] = 0.0f; acc_b[h] = 0.0f; }

    for (int c8 = 0; c8 < D_DIM / 32; ++c8) {   // 16 chunks of 32 d
        float4 xa[8], xb[8];
#pragma unroll
        for (int i = 0; i < 8; ++i) {
            xa[i] = xr0[c8 * 8 + i];
            xb[i] = xr1[c8 * 8 + i];
        }
#pragma unroll
        for (int h = 0; h < 8; ++h) {
            const float4* wr = reinterpret_cast<const float4*>(wlds + h * D_DIM + c8 * 32);
            float a = acc_a[h], b = acc_b[h];
#pragma unroll
            for (int i = 0; i < 8; ++i) {
                float4 wv = wr[i];   // wave-uniform addr -> LDS broadcast
                a = fmaf(xa[i].x, wv.x, a); a = fmaf(xa[i].y, wv.y, a);
                a = fmaf(xa[i].z, wv.z, a); a = fmaf(xa[i].w, wv.w, a);
                b = fmaf(xb[i].x, wv.x, b); b = fmaf(xb[i].y, wv.y, b);
                b = fmaf(xb[i].z, wv.z, b); b = fmaf(xb[i].w, wv.w, b);
            }
            acc_a[h] = a; acc_b[h] = b;
        }
    }

    const float s = 1.0f / (float)D_DIM;
    float* base = (hg < 2) ? qemb : kemb;
    const int ho = (hg & 1) * 8;
    if (n0 < n_nodes) {
        float* o = base + (size_t)n0 * 16 + ho;
        *reinterpret_cast<float4*>(o)     = make_float4(acc_a[0]*s, acc_a[1]*s, acc_a[2]*s, acc_a[3]*s);
        *reinterpret_cast<float4*>(o + 4) = make_float4(acc_a[4]*s, acc_a[5]*s, acc_a[6]*s, acc_a[7]*s);
    }
    if (n1 < n_nodes) {
        float* o = base + (size_t)n1 * 16 + ho;
        *reinterpret_cast<float4*>(o)     = make_float4(acc_b[0]*s, acc_b[1]*s, acc_b[2]*s, acc_b[3]*s);
        *reinterpret_cast<float4*>(o + 4) = make_float4(acc_b[4]*s, acc_b[5]*s, acc_b[6]*s, acc_b[7]*s);
    }
}

// ---------------- K3: edge aggregate + normalize + output matmul ----------------
// (unchanged structure; grid doubled to 2048 to shorten barrier convoys)
// dst = repeat(arange(N), K) by construction -> q_emb[dst[e]] == q_emb[n].
__global__ __launch_bounds__(512)
void agg_kernel(const int* __restrict__ adj, const float* __restrict__ ws,
                float* __restrict__ out, int n_nodes) {
    const float* nv    = ws + 16384;
    const float* nbias = ws + 24576;
    const float* nes   = ws + 25088;
    const float* qemb  = ws + 25104;
    const float* kemb  = qemb + (size_t)n_nodes * 16;
    const size_t NK = (size_t)n_nodes * K_EDGES;
    const int* srcp = adj;
    const int* mskp = adj + 2 * NK;

    __shared__ __align__(16) float attnS[2][8][16];

    const int t = threadIdx.x;
    const int w = t >> 6;
    const int lane = t & 63;
    const int e_lane = lane >> 1;         // edge 0..31
    const int h_ofs = (lane & 1) * 8;     // h 0-7 or 8-15

    float nvr[16];
#pragma unroll
    for (int j = 0; j < 4; ++j) {
        float4 v = *reinterpret_cast<const float4*>(nv + t * 16 + j * 4);
        nvr[4 * j + 0] = v.x; nvr[4 * j + 1] = v.y;
        nvr[4 * j + 2] = v.z; nvr[4 * j + 3] = v.w;
    }
    const float biasr = nbias[t];

    float nesr[8];
#pragma unroll
    for (int j = 0; j < 8; ++j) nesr[j] = nes[h_ofs + j];

    const int nbatches = (n_nodes + 7) / 8;
    int p = 0;
    for (int B = blockIdx.x; B < nbatches; B += gridDim.x) {
        const int n = B * 8 + w;
        if (n < n_nodes) {
            const size_t eb = (size_t)n * K_EDGES + e_lane;
            const int s  = srcp[eb];
            const int mk = mskp[eb];

            float4 qna = *reinterpret_cast<const float4*>(qemb + (size_t)n * 16 + h_ofs);
            float4 qnb = *reinterpret_cast<const float4*>(qemb + (size_t)n * 16 + h_ofs + 4);
            float qn[8] = {qna.x, qna.y, qna.z, qna.w, qnb.x, qnb.y, qnb.z, qnb.w};

            float4 ka = *reinterpret_cast<const float4*>(kemb + (size_t)s * 16 + h_ofs);
            float4 kb = *reinterpret_cast<const float4*>(kemb + (size_t)s * 16 + h_ofs + 4);

            const bool valid = (mk != 0);
            float pr[9];
            pr[0] = valid ? qn[0] * ka.x : 0.0f;
            pr[1] = valid ? qn[1] * ka.y : 0.0f;
            pr[2] = valid ? qn[2] * ka.z : 0.0f;
            pr[3] = valid ? qn[3] * ka.w : 0.0f;
            pr[4] = valid ? qn[4] * kb.x : 0.0f;
            pr[5] = valid ? qn[5] * kb.y : 0.0f;
            pr[6] = valid ? qn[6] * kb.z : 0.0f;
            pr[7] = valid ? qn[7] * kb.w : 0.0f;
            pr[8] = (float)mk;

#pragma unroll
            for (int m = 2; m <= 32; m <<= 1) {
#pragma unroll
                for (int j = 0; j < 9; ++j)
                    pr[j] += __shfl_xor(pr[j], m, 64);
            }

            const float rinv = 1.0f / (pr[8] + 1e-6f);

            float ss[8];
            float s8 = 0.0f;
#pragma unroll
            for (int j = 0; j < 8; ++j) {
                ss[j] = qn[j] * qn[j] * nesr[j] + pr[j] * rinv;
                s8 += ss[j];
            }
            const float tot = s8 + __shfl_xor(s8, 1, 64);
            const float invn = 1.0f / (tot + 1e-9f);

            if (lane < 2) {
#pragma unroll
                for (int j = 0; j < 8; ++j) attnS[p][w][h_ofs + j] = ss[j] * invn;
            }
        }
        __syncthreads();

#pragma unroll
        for (int w2 = 0; w2 < 8; ++w2) {
            const int n2 = B * 8 + w2;
            if (n2 < n_nodes) {
                const float4* arow = reinterpret_cast<const float4*>(attnS[p][w2]);
                float4 a0 = arow[0], a1 = arow[1], a2 = arow[2], a3 = arow[3];
                float acc = biasr;
                acc = fmaf(a0.x, nvr[0], acc);  acc = fmaf(a0.y, nvr[1], acc);
                acc = fmaf(a0.z, nvr[2], acc);  acc = fmaf(a0.w, nvr[3], acc);
                acc = fmaf(a1.x, nvr[4], acc);  acc = fmaf(a1.y, nvr[5], acc);
                acc = fmaf(a1.z, nvr[6], acc);  acc = fmaf(a1.w, nvr[7], acc);
                acc = fmaf(a2.x, nvr[8], acc);  acc = fmaf(a2.y, nvr[9], acc);
                acc = fmaf(a2.z, nvr[10], acc); acc = fmaf(a2.w, nvr[11], acc);
                acc = fmaf(a3.x, nvr[12], acc); acc = fmaf(a3.y, nvr[13], acc);
                acc = fmaf(a3.z, nvr[14], acc); acc = fmaf(a3.w, nvr[15], acc);
                out[(size_t)n2 * D_DIM + t] = acc;
            }
        }
        p ^= 1;
    }
}

extern "C" void kernel_launch(void* const* d_in, const int* in_sizes, int n_in,
                              void* d_out, int out_size, void* d_ws, size_t ws_size,
                              hipStream_t stream) {
    const float* x    = (const float*)d_in[0];
    const int*   adj  = (const int*)  d_in[1];
    const float* qw   = (const float*)d_in[2];
    const float* kw   = (const float*)d_in[3];
    const float* vw   = (const float*)d_in[4];
    const float* es   = (const float*)d_in[5];
    const float* bias = (const float*)d_in[6];
    float* out = (float*)d_out;

    const int n_nodes = in_sizes[0] / D_DIM;   // 100000

    float* ws_f  = (float*)d_ws;
    float* qemb  = ws_f + 25104;
    float* kemb  = qemb + (size_t)n_nodes * 16;

    prep_kernel<<<(25104 + 255) / 256, 256, 0, stream>>>(qw, kw, vw, es, bias, ws_f);

    const int nb_blocks = (n_nodes + NPB - 1) / NPB;   // 196
    embed_kernel<<<nb_blocks * 4, EMB_TPB, 0, stream>>>(x, ws_f, qemb, kemb, n_nodes);

    agg_kernel<<<2048, 512, 0, stream>>>(adj, ws_f, out, n_nodes);
}

// Round 6
// 655.187 us; speedup vs baseline: 1.6511x; 1.6511x over previous
//
#include <hip/hip_runtime.h>

#define D_DIM 512
#define H_HEADS 16
#define K_EDGES 32

// ws layout (floats):
//   wT    [0, 16384)        wT[h*512 + d], h<16 -> nonneg(q_w[h][d]), h>=16 -> nonneg(k_w[h-16][d])
//   nv    [16384, 24576)    nv[d*16 + h] = nonneg(v_w[d][h])
//   nbias [24576, 25088)
//   nes   [25088, 25104)    nonneg(ego_scale[h])
//   qemb  [25104, 25104 + N*16)
//   kemb  [25104 + N*16, 25104 + 2*N*16)

__device__ __forceinline__ float nonneg_precise(float w) {
    return w > 0.0f ? w + 1.0f : expf(w);   // == elu(w)+1 exactly
}

// ---------------- K1: weight prep ----------------
__global__ void prep_kernel(const float* __restrict__ qw, const float* __restrict__ kw,
                            const float* __restrict__ vw, const float* __restrict__ es,
                            const float* __restrict__ bias, float* __restrict__ ws) {
    int idx = blockIdx.x * blockDim.x + threadIdx.x;
    if (idx < 16384) {
        int h = idx >> 9, d = idx & 511;
        float v = (h < 16) ? qw[h * 512 + d] : kw[(h - 16) * 512 + d];
        ws[idx] = nonneg_precise(v);
    } else if (idx < 24576) {
        ws[idx] = nonneg_precise(vw[idx - 16384]);
    } else if (idx < 25088) {
        ws[idx] = nonneg_precise(bias[idx - 24576]);
    } else if (idx < 25104) {
        ws[idx] = nonneg_precise(es[idx - 25088]);
    }
}

// ---------------- K2: embeddings (v3) ----------------
// blockIdx = (node_tile, h_half). 128 threads (2 waves), 256 nodes/block,
// 16 heads/block. Weights (16x512 = 32KB) staged in LDS once; x staged in
// LDS chunks of 16 d (coalesced 64B row-segments, every fetched line fully
// consumed). Thread: 2 nodes x 16 h -> each uniform weight ds_read_b128
// (broadcast, conflict-free) feeds 8 FMAs. x rows padded to 20 floats ->
// 8-way bank spread (b128 floor). LDS 52KB -> 3 blocks/CU = 6 waves/CU.
#define EMB_TPB 128
#define EMB_NODES 256
#define EMB_CH 16
#define XSTRIDE 20   // 16 + 4 pad floats

__global__ __launch_bounds__(EMB_TPB)
void embed_kernel(const float* __restrict__ x, const float* __restrict__ ws,
                  float* __restrict__ qemb, float* __restrict__ kemb, int n_nodes) {
    __shared__ __align__(16) float wlds[16 * D_DIM];             // 32 KB
    __shared__ __align__(16) float xlds[EMB_NODES * XSTRIDE];    // 20 KB
    const int t  = threadIdx.x;
    const int hg = blockIdx.x & 1;      // 0 -> q heads, 1 -> k heads
    const int nb = blockIdx.x >> 1;
    const int n0 = nb * EMB_NODES;

    // stage this half's 16 weight rows (contiguous in wT): 2048 float4 / 128 thr
    {
        const float4* src = reinterpret_cast<const float4*>(ws + (size_t)hg * 16 * D_DIM);
        float4* dst = reinterpret_cast<float4*>(wlds);
#pragma unroll
        for (int i = 0; i < 16; ++i) dst[t + i * EMB_TPB] = src[t + i * EMB_TPB];
    }
    // first in-loop __syncthreads() orders weight staging before first use

    float acc_a[16], acc_b[16];
#pragma unroll
    for (int h = 0; h < 16; ++h) { acc_a[h] = 0.0f; acc_b[h] = 0.0f; }

    const int la = t, lb = t + EMB_TPB;      // my two local nodes

    for (int c = 0; c < D_DIM / EMB_CH; ++c) {   // 32 chunks of 16 d
        __syncthreads();   // prev chunk's readers done (and weights staged, c=0)
        // stage 256 rows x 16 d: f = t + i*128; row = f>>2 (4 lanes/row), j = f&3
#pragma unroll
        for (int i = 0; i < 8; ++i) {
            int f = t + i * EMB_TPB;
            int row = f >> 2, j = f & 3;
            int g = n0 + row; g = (g < n_nodes) ? g : 0;   // clamp loads
            float4 v = *reinterpret_cast<const float4*>(x + (size_t)g * D_DIM + c * EMB_CH + j * 4);
            *reinterpret_cast<float4*>(xlds + row * XSTRIDE + j * 4) = v;
        }
        __syncthreads();

        // compute: per d-quad, 2 x-reads + 16 uniform w-reads -> 128 FMAs
#pragma unroll
        for (int j = 0; j < 4; ++j) {
            float4 xa = *reinterpret_cast<const float4*>(xlds + la * XSTRIDE + j * 4);
            float4 xb = *reinterpret_cast<const float4*>(xlds + lb * XSTRIDE + j * 4);
#pragma unroll
            for (int h = 0; h < 16; ++h) {
                float4 wv = *reinterpret_cast<const float4*>(wlds + h * D_DIM + c * EMB_CH + j * 4);
                float a = acc_a[h], b = acc_b[h];
                a = fmaf(xa.x, wv.x, a); a = fmaf(xa.y, wv.y, a);
                a = fmaf(xa.z, wv.z, a); a = fmaf(xa.w, wv.w, a);
                b = fmaf(xb.x, wv.x, b); b = fmaf(xb.y, wv.y, b);
                b = fmaf(xb.z, wv.z, b); b = fmaf(xb.w, wv.w, b);
                acc_a[h] = a; acc_b[h] = b;
            }
        }
    }

    const float s = 1.0f / (float)D_DIM;
    float* base = hg ? kemb : qemb;
    const int ga = n0 + la, gb = n0 + lb;
    if (ga < n_nodes) {
        float* o = base + (size_t)ga * 16;
#pragma unroll
        for (int k = 0; k < 4; ++k)
            *reinterpret_cast<float4*>(o + 4 * k) =
                make_float4(acc_a[4*k]*s, acc_a[4*k+1]*s, acc_a[4*k+2]*s, acc_a[4*k+3]*s);
    }
    if (gb < n_nodes) {
        float* o = base + (size_t)gb * 16;
#pragma unroll
        for (int k = 0; k < 4; ++k)
            *reinterpret_cast<float4*>(o + 4 * k) =
                make_float4(acc_b[4*k]*s, acc_b[4*k+1]*s, acc_b[4*k+2]*s, acc_b[4*k+3]*s);
    }
}

// ---------------- K3: edge aggregate + normalize + output matmul ----------------
// (unchanged; grid 2048)  dst = repeat(arange(N), K) -> q_emb[dst[e]] == q_emb[n].
__global__ __launch_bounds__(512)
void agg_kernel(const int* __restrict__ adj, const float* __restrict__ ws,
                float* __restrict__ out, int n_nodes) {
    const float* nv    = ws + 16384;
    const float* nbias = ws + 24576;
    const float* nes   = ws + 25088;
    const float* qemb  = ws + 25104;
    const float* kemb  = qemb + (size_t)n_nodes * 16;
    const size_t NK = (size_t)n_nodes * K_EDGES;
    const int* srcp = adj;
    const int* mskp = adj + 2 * NK;

    __shared__ __align__(16) float attnS[2][8][16];

    const int t = threadIdx.x;
    const int w = t >> 6;
    const int lane = t & 63;
    const int e_lane = lane >> 1;
    const int h_ofs = (lane & 1) * 8;

    float nvr[16];
#pragma unroll
    for (int j = 0; j < 4; ++j) {
        float4 v = *reinterpret_cast<const float4*>(nv + t * 16 + j * 4);
        nvr[4 * j + 0] = v.x; nvr[4 * j + 1] = v.y;
        nvr[4 * j + 2] = v.z; nvr[4 * j + 3] = v.w;
    }
    const float biasr = nbias[t];

    float nesr[8];
#pragma unroll
    for (int j = 0; j < 8; ++j) nesr[j] = nes[h_ofs + j];

    const int nbatches = (n_nodes + 7) / 8;
    int p = 0;
    for (int B = blockIdx.x; B < nbatches; B += gridDim.x) {
        const int n = B * 8 + w;
        if (n < n_nodes) {
            const size_t eb = (size_t)n * K_EDGES + e_lane;
            const int s  = srcp[eb];
            const int mk = mskp[eb];

            float4 qna = *reinterpret_cast<const float4*>(qemb + (size_t)n * 16 + h_ofs);
            float4 qnb = *reinterpret_cast<const float4*>(qemb + (size_t)n * 16 + h_ofs + 4);
            float qn[8] = {qna.x, qna.y, qna.z, qna.w, qnb.x, qnb.y, qnb.z, qnb.w};

            float4 ka = *reinterpret_cast<const float4*>(kemb + (size_t)s * 16 + h_ofs);
            float4 kb = *reinterpret_cast<const float4*>(kemb + (size_t)s * 16 + h_ofs + 4);

            const bool valid = (mk != 0);
            float pr[9];
            pr[0] = valid ? qn[0] * ka.x : 0.0f;
            pr[1] = valid ? qn[1] * ka.y : 0.0f;
            pr[2] = valid ? qn[2] * ka.z : 0.0f;
            pr[3] = valid ? qn[3] * ka.w : 0.0f;
            pr[4] = valid ? qn[4] * kb.x : 0.0f;
            pr[5] = valid ? qn[5] * kb.y : 0.0f;
            pr[6] = valid ? qn[6] * kb.z : 0.0f;
            pr[7] = valid ? qn[7] * kb.w : 0.0f;
            pr[8] = (float)mk;

#pragma unroll
            for (int m = 2; m <= 32; m <<= 1) {
#pragma unroll
                for (int j = 0; j < 9; ++j)
                    pr[j] += __shfl_xor(pr[j], m, 64);
            }

            const float rinv = 1.0f / (pr[8] + 1e-6f);

            float ss[8];
            float s8 = 0.0f;
#pragma unroll
            for (int j = 0; j < 8; ++j) {
                ss[j] = qn[j] * qn[j] * nesr[j] + pr[j] * rinv;
                s8 += ss[j];
            }
            const float tot = s8 + __shfl_xor(s8, 1, 64);
            const float invn = 1.0f / (tot + 1e-9f);

            if (lane < 2) {
#pragma unroll
                for (int j = 0; j < 8; ++j) attnS[p][w][h_ofs + j] = ss[j] * invn;
            }
        }
        __syncthreads();

#pragma unroll
        for (int w2 = 0; w2 < 8; ++w2) {
            const int n2 = B * 8 + w2;
            if (n2 < n_nodes) {
                const float4* arow = reinterpret_cast<const float4*>(attnS[p][w2]);
                float4 a0 = arow[0], a1 = arow[1], a2 = arow[2], a3 = arow[3];
                float acc = biasr;
                acc = fmaf(a0.x, nvr[0], acc);  acc = fmaf(a0.y, nvr[1], acc);
                acc = fmaf(a0.z, nvr[2], acc);  acc = fmaf(a0.w, nvr[3], acc);
                acc = fmaf(a1.x, nvr[4], acc);  acc = fmaf(a1.y, nvr[5], acc);
                acc = fmaf(a1.z, nvr[6], acc);  acc = fmaf(a1.w, nvr[7], acc);
                acc = fmaf(a2.x, nvr[8], acc);  acc = fmaf(a2.y, nvr[9], acc);
                acc = fmaf(a2.z, nvr[10], acc); acc = fmaf(a2.w, nvr[11], acc);
                acc = fmaf(a3.x, nvr[12], acc); acc = fmaf(a3.y, nvr[13], acc);
                acc = fmaf(a3.z, nvr[14], acc); acc = fmaf(a3.w, nvr[15], acc);
                out[(size_t)n2 * D_DIM + t] = acc;
            }
        }
        p ^= 1;
    }
}

extern "C" void kernel_launch(void* const* d_in, const int* in_sizes, int n_in,
                              void* d_out, int out_size, void* d_ws, size_t ws_size,
                              hipStream_t stream) {
    const float* x    = (const float*)d_in[0];
    const int*   adj  = (const int*)  d_in[1];
    const float* qw   = (const float*)d_in[2];
    const float* kw   = (const float*)d_in[3];
    const float* vw   = (const float*)d_in[4];
    const float* es   = (const float*)d_in[5];
    const float* bias = (const float*)d_in[6];
    float* out = (float*)d_out;

    const int n_nodes = in_sizes[0] / D_DIM;   // 100000

    float* ws_f  = (float*)d_ws;
    float* qemb  = ws_f + 25104;
    float* kemb  = qemb + (size_t)n_nodes * 16;

    prep_kernel<<<(25104 + 255) / 256, 256, 0, stream>>>(qw, kw, vw, es, bias, ws_f);

    const int ntiles = (n_nodes + EMB_NODES - 1) / EMB_NODES;   // 391
    embed_kernel<<<ntiles * 2, EMB_TPB, 0, stream>>>(x, ws_f, qemb, kemb, n_nodes);

    agg_kernel<<<2048, 512, 0, stream>>>(adj, ws_f, out, n_nodes);
}

// Round 14
// 453.244 us; speedup vs baseline: 2.3868x; 1.4456x over previous
//
#include <hip/hip_runtime.h>

#define D_DIM 512
#define H_HEADS 16
#define K_EDGES 32

// ws layout (floats):
//   wTT   [0, 16384)        wTT[d*32 + h]: h<16 -> nonneg(q_w[h][d]), h>=16 -> nonneg(k_w[h-16][d])
//   nv    [16384, 24576)    nv[d*16 + h] = nonneg(v_w[d][h])
//   nbias [24576, 25088)
//   nes   [25088, 25104)    nonneg(ego_scale[h])
//   qemb  [25104, 25104 + N*16)
//   kemb  [25104 + N*16, 25104 + 2*N*16)

__device__ __forceinline__ float nonneg_precise(float w) {
    return w > 0.0f ? w + 1.0f : expf(w);   // == elu(w)+1 exactly
}

// ---------------- K1: weight prep ----------------
__global__ void prep_kernel(const float* __restrict__ qw, const float* __restrict__ kw,
                            const float* __restrict__ vw, const float* __restrict__ es,
                            const float* __restrict__ bias, float* __restrict__ ws) {
    int idx = blockIdx.x * blockDim.x + threadIdx.x;
    if (idx < 16384) {
        int d = idx >> 5, h = idx & 31;   // TRANSPOSED: wTT[d][h]
        float v = (h < 16) ? qw[h * 512 + d] : kw[(h - 16) * 512 + d];
        ws[idx] = nonneg_precise(v);
    } else if (idx < 24576) {
        ws[idx] = nonneg_precise(vw[idx - 16384]);
    } else if (idx < 25088) {
        ws[idx] = nonneg_precise(bias[idx - 24576]);
    } else if (idx < 25104) {
        ws[idx] = nonneg_precise(es[idx - 25088]);
    }
}

// ---------------- K2: embeddings (v4) ----------------
// ONE WAVE per block, 64 nodes, hg selects q-heads or k-heads (16 accs).
// Weights via block-uniform s_load from wTT[d*32 + hg*16] (SGPR broadcast,
// zero VALU/LDS cost). x staged per-wave in LDS, transposed [32 d][65]:
// compute reads bank (d+l)%32 -> 2-way floor; no __syncthreads anywhere.
// Next chunk's 8x b128 global loads issued into registers BEFORE compute
// (T14 split) so HBM latency hides under the 512-FMA compute phase.
#define XW 65

__global__ __launch_bounds__(64)
void embed_kernel(const float* __restrict__ x, const float* __restrict__ ws,
                  float* __restrict__ qemb, float* __restrict__ kemb, int n_nodes) {
    __shared__ float xl[32 * XW];   // 8.32 KB
    const int l  = threadIdx.x;
    const int hg = blockIdx.x & 1;        // 0 -> q heads, 1 -> k heads
    const int nt = blockIdx.x >> 1;
    const int n0 = nt * 64;
    const float* wTT = ws;

    float acc[16];
#pragma unroll
    for (int h = 0; h < 16; ++h) acc[h] = 0.0f;

    // staging geometry: f = l + i*64 -> node row (l>>3)+8i, d-quad j = l&7
    const int j = l & 7;
    int gn[8];
#pragma unroll
    for (int i = 0; i < 8; ++i) {
        int g = n0 + (l >> 3) + 8 * i;
        gn[i] = (g < n_nodes) ? g : 0;    // clamp loads, guard stores later
    }

    float4 r[8];
#pragma unroll
    for (int i = 0; i < 8; ++i)
        r[i] = *reinterpret_cast<const float4*>(x + (size_t)gn[i] * D_DIM + j * 4);

    for (int c = 0; c < 16; ++c) {        // 16 chunks of 32 d
        // write prefetched chunk to LDS transposed: d-local = 4j+jj, node = row
#pragma unroll
        for (int i = 0; i < 8; ++i) {
            int row = (l >> 3) + 8 * i;
            xl[(4 * j + 0) * XW + row] = r[i].x;
            xl[(4 * j + 1) * XW + row] = r[i].y;
            xl[(4 * j + 2) * XW + row] = r[i].z;
            xl[(4 * j + 3) * XW + row] = r[i].w;
        }
        // issue next chunk's global loads now; they fly during compute
        if (c < 15) {
#pragma unroll
            for (int i = 0; i < 8; ++i)
                r[i] = *reinterpret_cast<const float4*>(
                    x + (size_t)gn[i] * D_DIM + (c + 1) * 32 + j * 4);
        }
        // compute: per d, 1 near-conflict-free ds_read_b32 + 16 FMA (weights = SGPR)
        const float* wc = wTT + (size_t)c * 32 * 32 + hg * 16;
#pragma unroll 4
        for (int dd = 0; dd < 32; ++dd) {
            float xv = xl[dd * XW + l];
            const float* wr = wc + dd * 32;
#pragma unroll
            for (int h = 0; h < 16; ++h)
                acc[h] = fmaf(xv, wr[h], acc[h]);
        }
    }

    const int n = n0 + l;
    if (n < n_nodes) {
        const float s = 1.0f / (float)D_DIM;
        float* o = (hg ? kemb : qemb) + (size_t)n * 16;
#pragma unroll
        for (int k = 0; k < 4; ++k)
            *reinterpret_cast<float4*>(o + 4 * k) =
                make_float4(acc[4*k]*s, acc[4*k+1]*s, acc[4*k+2]*s, acc[4*k+3]*s);
    }
}

// ---------------- K3: edge aggregate + normalize + output matmul ----------------
// (unchanged; grid 2048)  dst = repeat(arange(N), K) -> q_emb[dst[e]] == q_emb[n].
__global__ __launch_bounds__(512)
void agg_kernel(const int* __restrict__ adj, const float* __restrict__ ws,
                float* __restrict__ out, int n_nodes) {
    const float* nv    = ws + 16384;
    const float* nbias = ws + 24576;
    const float* nes   = ws + 25088;
    const float* qemb  = ws + 25104;
    const float* kemb  = qemb + (size_t)n_nodes * 16;
    const size_t NK = (size_t)n_nodes * K_EDGES;
    const int* srcp = adj;
    const int* mskp = adj + 2 * NK;

    __shared__ __align__(16) float attnS[2][8][16];

    const int t = threadIdx.x;
    const int w = t >> 6;
    const int lane = t & 63;
    const int e_lane = lane >> 1;
    const int h_ofs = (lane & 1) * 8;

    float nvr[16];
#pragma unroll
    for (int j = 0; j < 4; ++j) {
        float4 v = *reinterpret_cast<const float4*>(nv + t * 16 + j * 4);
        nvr[4 * j + 0] = v.x; nvr[4 * j + 1] = v.y;
        nvr[4 * j + 2] = v.z; nvr[4 * j + 3] = v.w;
    }
    const float biasr = nbias[t];

    float nesr[8];
#pragma unroll
    for (int j = 0; j < 8; ++j) nesr[j] = nes[h_ofs + j];

    const int nbatches = (n_nodes + 7) / 8;
    int p = 0;
    for (int B = blockIdx.x; B < nbatches; B += gridDim.x) {
        const int n = B * 8 + w;
        if (n < n_nodes) {
            const size_t eb = (size_t)n * K_EDGES + e_lane;
            const int s  = srcp[eb];
            const int mk = mskp[eb];

            float4 qna = *reinterpret_cast<const float4*>(qemb + (size_t)n * 16 + h_ofs);
            float4 qnb = *reinterpret_cast<const float4*>(qemb + (size_t)n * 16 + h_ofs + 4);
            float qn[8] = {qna.x, qna.y, qna.z, qna.w, qnb.x, qnb.y, qnb.z, qnb.w};

            float4 ka = *reinterpret_cast<const float4*>(kemb + (size_t)s * 16 + h_ofs);
            float4 kb = *reinterpret_cast<const float4*>(kemb + (size_t)s * 16 + h_ofs + 4);

            const bool valid = (mk != 0);
            float pr[9];
            pr[0] = valid ? qn[0] * ka.x : 0.0f;
            pr[1] = valid ? qn[1] * ka.y : 0.0f;
            pr[2] = valid ? qn[2] * ka.z : 0.0f;
            pr[3] = valid ? qn[3] * ka.w : 0.0f;
            pr[4] = valid ? qn[4] * kb.x : 0.0f;
            pr[5] = valid ? qn[5] * kb.y : 0.0f;
            pr[6] = valid ? qn[6] * kb.z : 0.0f;
            pr[7] = valid ? qn[7] * kb.w : 0.0f;
            pr[8] = (float)mk;

#pragma unroll
            for (int m = 2; m <= 32; m <<= 1) {
#pragma unroll
                for (int j = 0; j < 9; ++j)
                    pr[j] += __shfl_xor(pr[j], m, 64);
            }

            const float rinv = 1.0f / (pr[8] + 1e-6f);

            float ss[8];
            float s8 = 0.0f;
#pragma unroll
            for (int j = 0; j < 8; ++j) {
                ss[j] = qn[j] * qn[j] * nesr[j] + pr[j] * rinv;
                s8 += ss[j];
            }
            const float tot = s8 + __shfl_xor(s8, 1, 64);
            const float invn = 1.0f / (tot + 1e-9f);

            if (lane < 2) {
#pragma unroll
                for (int j = 0; j < 8; ++j) attnS[p][w][h_ofs + j] = ss[j] * invn;
            }
        }
        __syncthreads();

#pragma unroll
        for (int w2 = 0; w2 < 8; ++w2) {
            const int n2 = B * 8 + w2;
            if (n2 < n_nodes) {
                const float4* arow = reinterpret_cast<const float4*>(attnS[p][w2]);
                float4 a0 = arow[0], a1 = arow[1], a2 = arow[2], a3 = arow[3];
                float acc = biasr;
                acc = fmaf(a0.x, nvr[0], acc);  acc = fmaf(a0.y, nvr[1], acc);
                acc = fmaf(a0.z, nvr[2], acc);  acc = fmaf(a0.w, nvr[3], acc);
                acc = fmaf(a1.x, nvr[4], acc);  acc = fmaf(a1.y, nvr[5], acc);
                acc = fmaf(a1.z, nvr[6], acc);  acc = fmaf(a1.w, nvr[7], acc);
                acc = fmaf(a2.x, nvr[8], acc);  acc = fmaf(a2.y, nvr[9], acc);
                acc = fmaf(a2.z, nvr[10], acc); acc = fmaf(a2.w, nvr[11], acc);
                acc = fmaf(a3.x, nvr[12], acc); acc = fmaf(a3.y, nvr[13], acc);
                acc = fmaf(a3.z, nvr[14], acc); acc = fmaf(a3.w, nvr[15], acc);
                out[(size_t)n2 * D_DIM + t] = acc;
            }
        }
        p ^= 1;
    }
}

extern "C" void kernel_launch(void* const* d_in, const int* in_sizes, int n_in,
                              void* d_out, int out_size, void* d_ws, size_t ws_size,
                              hipStream_t stream) {
    const float* x    = (const float*)d_in[0];
    const int*   adj  = (const int*)  d_in[1];
    const float* qw   = (const float*)d_in[2];
    const float* kw   = (const float*)d_in[3];
    const float* vw   = (const float*)d_in[4];
    const float* es   = (const float*)d_in[5];
    const float* bias = (const float*)d_in[6];
    float* out = (float*)d_out;

    const int n_nodes = in_sizes[0] / D_DIM;   // 100000

    float* ws_f  = (float*)d_ws;
    float* qemb  = ws_f + 25104;
    float* kemb  = qemb + (size_t)n_nodes * 16;

    prep_kernel<<<(25104 + 255) / 256, 256, 0, stream>>>(qw, kw, vw, es, bias, ws_f);

    const int ntiles = (n_nodes + 63) / 64;   // 1563
    embed_kernel<<<ntiles * 2, 64, 0, stream>>>(x, ws_f, qemb, kemb, n_nodes);

    agg_kernel<<<2048, 512, 0, stream>>>(adj, ws_f, out, n_nodes);
}